// Round 12
// baseline (101.052 us; speedup 1.0000x reference)
//
#include <hip/hip_runtime.h>
#include <hip/hip_bf16.h>

// ---- problem constants ----
#define BATCH   4096
#define FEAT    1024
#define NTREES  10
#define NNODES  255
#define NLEAF   256
#define NCLS    1000
#define KTOT    2560          // NTREES*NLEAF

typedef __attribute__((ext_vector_type(8)))  short bf16x8;
typedef __attribute__((ext_vector_type(4)))  float f32x4;
typedef __attribute__((ext_vector_type(16))) float f32x16;

// workspace layout (bytes)
#define OFF_XB 0u             // xb bf16 [4096][1024]      8,388,608
#define OFF_WT 8388608u       // wT bf16 [10][256][1024]   5,242,880
#define OFF_PT 13631488u      // pT bf16 [1024][2560]      5,242,880
#define OFF_RT 18874368u      // route bf16 [4096][2560]  20,971,520

#define WAITVM(N) asm volatile("s_waitcnt vmcnt(" #N ")" ::: "memory")
#define WAITLGKM() asm volatile("s_waitcnt lgkmcnt(0)" ::: "memory")
#define BAR() __builtin_amdgcn_s_barrier()

__device__ __forceinline__ void load_lds16(const void* g, void* l) {
    __builtin_amdgcn_global_load_lds(
        (const __attribute__((address_space(1))) unsigned int*)g,
        (__attribute__((address_space(3))) unsigned int*)l, 16, 0, 0);
}

// ---------------- fused conversion kernel (R4, verified) ----------------
__global__ void k_cvt_all(const float* __restrict__ x, const float* __restrict__ w,
                          const float* __restrict__ p,
                          __hip_bfloat16* __restrict__ xb,
                          __hip_bfloat16* __restrict__ wT,
                          __hip_bfloat16* __restrict__ pT) {
    __shared__ float tile[32][33];
    const int bid = blockIdx.x;
    const int tid = threadIdx.x;

    if (bid < 4096) {
        int i = bid * 256 + tid;
        float4 v = reinterpret_cast<const float4*>(x)[i];
        union { ushort4 u; __hip_bfloat16 h[4]; } o;
        o.h[0] = __float2bfloat16(v.x);
        o.h[1] = __float2bfloat16(v.y);
        o.h[2] = __float2bfloat16(v.z);
        o.h[3] = __float2bfloat16(v.w);
        reinterpret_cast<ushort4*>(xb)[i] = o.u;
    } else if (bid < 6656) {
        int idx = bid - 4096;              // 2560: t(10) x fb(32) x nb(8)
        int t  = idx >> 8;
        int fb = ((idx >> 3) & 31) * 32;
        int nb = (idx & 7) * 32;
        int tx = tid & 31, ty = tid >> 5;
#pragma unroll
        for (int j = 0; j < 4; ++j) {
            int f = fb + ty + j * 8;
            int n = nb + tx;
            float v = (n < NNODES) ? w[((size_t)t * FEAT + f) * NNODES + n] : 0.f;
            tile[ty + j * 8][tx] = v;
        }
        __syncthreads();
#pragma unroll
        for (int j = 0; j < 4; ++j) {
            int n = nb + ty + j * 8;
            int f = fb + tx;
            wT[((size_t)t * NLEAF + n) * FEAT + f] = __float2bfloat16(tile[tx][ty + j * 8]);
        }
    } else {
        int idx = bid - 6656;              // 2560: kb(80) x cb(32)
        int cb = (idx & 31) * 32;
        int kb = (idx >> 5) * 32;
        int tx = tid & 31, ty = tid >> 5;
#pragma unroll
        for (int j = 0; j < 4; ++j) {
            int k = kb + ty + j * 8;
            int c = cb + tx;
            float v = (c < NCLS) ? p[(size_t)k * NCLS + c] * 0.1f : 0.f;
            tile[ty + j * 8][tx] = v;
        }
        __syncthreads();
#pragma unroll
        for (int j = 0; j < 4; ++j) {
            int c = cb + ty + j * 8;
            int k = kb + tx;
            pT[(size_t)c * KTOT + k] = __float2bfloat16(tile[tx][ty + j * 8]);
        }
    }
}

// ---------------- GEMM1 + sigmoid + routing ----------------
// 32x32x16 MFMA version: tile 64(M) x 256(N=one tree), BK=64, 256 thr = 4 waves
// (1M x 4N), wave tile 64x64 -> 2x FLOP per LDS byte vs 16x16x32, per-tile LDS
// traffic 136->104KB. Single 40KB buffer -> 3-4 blocks/CU co-resident.
// A/B operand: lane holds row/col = lane&31, k = (lane>>5)*8+j (16B contiguous).
// C/D: col = lane&31, row = (reg&3)+8*(reg>>2)+4*(lane>>5)  [m74/m101].
__global__ __launch_bounds__(256) void k_gemm1_route(
        const __hip_bfloat16* __restrict__ xb,
        const __hip_bfloat16* __restrict__ wT,
        __hip_bfloat16* __restrict__ route) {
    __shared__ __align__(16) char smem[40960];    // A 8KB + B 32KB; Ds[64][132] f32 reuse

    const int wg = blockIdx.x;                    // 640 blocks
    const int sw = (wg & 7) * 80 + (wg >> 3);     // 8 XCD x 80 (tree-grouped per XCD)
    const int bm = sw & 63;
    const int tr = sw >> 6;

    const int tid = threadIdx.x;
    const int lane = tid & 63, wn = tid >> 6;     // 4 waves, wave wn owns cols wn*64..+64

    f32x16 acc[2][2] = {};                        // [mf(rows 32*mf)][nf(cols wn*64+nf*32)]

    // ---- hoisted staging bases (pre-swizzled source, linear dest) ----
    // chunk d = q*256+tid; R = d>>3; gc = (d&7)^(R&7); q*256 keeps gc invariant.
    const char* gA; const char* gB; int lA, lB;
    {
        int R = tid >> 3, gc = (tid & 7) ^ (R & 7);
        gA = (const char*)xb + ((size_t)(bm * 64 + R)) * 2048 + gc * 16;
        gB = (const char*)wT + ((size_t)(tr * 256 + R)) * 2048 + gc * 16;
        lA = tid * 16;
        lB = 8192 + tid * 16;
    }

    // ---- hoisted fragment-read offsets ----
    int offA[2][4], offB[2][4];                   // [mf|nf][kk]
#pragma unroll
    for (int kk = 0; kk < 4; ++kk) {
        int s = kk * 2 + (lane >> 5);             // 16B chunk within 128B row
#pragma unroll
        for (int mf = 0; mf < 2; ++mf) {
            int ra = mf * 32 + (lane & 31);
            offA[mf][kk] = ra * 128 + ((s ^ (ra & 7)) << 4);
        }
#pragma unroll
        for (int nf = 0; nf < 2; ++nf) {
            int rb = wn * 64 + nf * 32 + (lane & 31);
            offB[nf][kk] = 8192 + rb * 128 + ((s ^ (rb & 7)) << 4);
        }
    }

#pragma unroll 4
    for (int t = 0; t < 16; ++t) {
        // stage tile t (10 loads/thread): A 2, B 8
        load_lds16(gA + t * 128,         smem + lA);
        load_lds16(gA + 65536 + t * 128, smem + lA + 4096);
#pragma unroll
        for (int q = 0; q < 8; ++q)
            load_lds16(gB + q * 65536 + t * 128, smem + lB + q * 4096);
        __syncthreads();                          // tile visible

        bf16x8 a[2][4], b[2][4];
#pragma unroll
        for (int kk = 0; kk < 4; ++kk) {
#pragma unroll
            for (int mf = 0; mf < 2; ++mf)
                a[mf][kk] = *(const bf16x8*)(smem + offA[mf][kk]);
#pragma unroll
            for (int nf = 0; nf < 2; ++nf)
                b[nf][kk] = *(const bf16x8*)(smem + offB[nf][kk]);
        }
#pragma unroll
        for (int kk = 0; kk < 4; ++kk)
#pragma unroll
            for (int mf = 0; mf < 2; ++mf)
#pragma unroll
                for (int nf = 0; nf < 2; ++nf)
                    acc[mf][nf] = __builtin_amdgcn_mfma_f32_32x32x16_bf16(
                        a[mf][kk], b[nf][kk], acc[mf][nf], 0, 0, 0);
        __syncthreads();                          // reads retired -> safe to re-stage
    }

    // ---- epilogue: sigmoid nodes 0..126 -> Ds; level-7 from regs; 2 leaves packed
    float* Ds = (float*)smem;                     // [64][132] fp32 = 33.8KB
#pragma unroll
    for (int mf = 0; mf < 2; ++mf)
#pragma unroll
        for (int nf = 0; nf < 2; ++nf) {
            int col = wn * 64 + nf * 32 + (lane & 31);
            if (col < 127) {
#pragma unroll
                for (int r = 0; r < 16; ++r) {
                    int row = mf * 32 + (r & 3) + 8 * (r >> 2) + 4 * (lane >> 5);
                    float z = acc[mf][nf][r];
                    Ds[row * 132 + col] = 1.f / (1.f + __expf(-z));
                }
            }
        }
    __syncthreads();
#pragma unroll
    for (int mf = 0; mf < 2; ++mf)
#pragma unroll
        for (int nf = 0; nf < 2; ++nf) {
            int col = wn * 64 + nf * 32 + (lane & 31);
            if (col >= 127 && col <= 254) {
                int pnode = col - 127;
#pragma unroll
                for (int r = 0; r < 16; ++r) {
                    int row = mf * 32 + (r & 3) + 8 * (r >> 2) + 4 * (lane >> 5);
                    float prefix = 1.f;
#pragma unroll
                    for (int l = 0; l < 7; ++l) {
                        int node = (1 << l) - 1 + (pnode >> (7 - l));
                        float v = Ds[row * 132 + node];
                        prefix *= (((pnode >> (6 - l)) & 1) == 0) ? v : (1.f - v);
                    }
                    float wv = 1.f / (1.f + __expf(-acc[mf][nf][r]));
                    union { unsigned int u; __hip_bfloat16 h[2]; } pk;
                    pk.h[0] = __float2bfloat16(prefix * wv);
                    pk.h[1] = __float2bfloat16(prefix * (1.f - wv));
                    int bb = bm * 64 + row;
                    *(unsigned int*)(route + (size_t)bb * KTOT + tr * NLEAF + 2 * pnode) = pk.u;
                }
            }
        }
}

// ---------------- GEMM2 + clip (R9/R10, verified) ----------------
// tile 128x128 (grid 256 = 1 round), BK=64, 512 thr = 8 waves (2M x 4N, wave 64x32).
// dbuf 2 x 32KB = 64KB, WAITVM(4), addresses hoisted.
__global__ __launch_bounds__(512) void k_gemm2(
        const __hip_bfloat16* __restrict__ route,
        const __hip_bfloat16* __restrict__ pT,
        float* __restrict__ out) {
    __shared__ __align__(16) char smem[65536];

    const int wg = blockIdx.x;                    // 256 blocks
    const int sw = (wg & 7) * 32 + (wg >> 3);     // 8 XCD x 32
    const int bm = sw >> 3;
    const int bn = sw & 7;

    const int tid = threadIdx.x;
    const int lane = tid & 63, wid = tid >> 6;
    const int wm = wid >> 2, wn = wid & 3;        // 2M x 4N, wave 64x32

    f32x4 acc[4][2] = {};

    const char* gA[2]; int lA[2];
    const char* gB[2]; int lB[2];
#pragma unroll
    for (int q = 0; q < 2; ++q) {
        int d = q * 512 + tid, R = d >> 3, c = d & 7, gc = c ^ (R & 7);
        gA[q] = (const char*)route + ((size_t)(bm * 128 + R)) * 5120 + gc * 16;
        lA[q] = d * 16;
        gB[q] = (const char*)pT + ((size_t)(bn * 128 + R)) * 5120 + gc * 16;
        lB[q] = 16384 + d * 16;
    }
    int offA[4][2];                               // [mf][ks]
#pragma unroll
    for (int mf = 0; mf < 4; ++mf)
#pragma unroll
        for (int ks = 0; ks < 2; ++ks) {
            int ra = wm * 64 + mf * 16 + (lane & 15);
            int s  = ks * 4 + (lane >> 4);
            offA[mf][ks] = ra * 128 + ((s ^ (ra & 7)) << 4);
        }
    int offB[2][2];                               // [ks][nf]
#pragma unroll
    for (int ks = 0; ks < 2; ++ks)
#pragma unroll
        for (int nf = 0; nf < 2; ++nf) {
            int rb = wn * 32 + nf * 16 + (lane & 15);
            int s  = ks * 4 + (lane >> 4);
            offB[ks][nf] = 16384 + rb * 128 + ((s ^ (rb & 7)) << 4);
        }

    auto stage = [&](int t) {                     // 4 loads/thread
        char* base = smem + (t & 1) * 32768;
#pragma unroll
        for (int q = 0; q < 2; ++q) {
            load_lds16(gA[q] + (size_t)t * 128, base + lA[q]);
            load_lds16(gB[q] + (size_t)t * 128, base + lB[q]);
        }
    };

    stage(0);

    for (int to = 0; to < 5; ++to) {
#pragma unroll
        for (int ti = 0; ti < 8; ++ti) {
            const int t = to * 8 + ti;
            if (t < 39) { stage(t + 1); WAITVM(4); }
            else        { WAITVM(0); }
            BAR();

            const char* As = smem + (t & 1) * 32768;
#pragma unroll
            for (int ks = 0; ks < 2; ++ks) {
                bf16x8 a[4], b[2];
#pragma unroll
                for (int mf = 0; mf < 4; ++mf)
                    a[mf] = *(const bf16x8*)(As + offA[mf][ks]);
#pragma unroll
                for (int nf = 0; nf < 2; ++nf)
                    b[nf] = *(const bf16x8*)(As + offB[ks][nf]);
#pragma unroll
                for (int mf = 0; mf < 4; ++mf)
#pragma unroll
                    for (int nf = 0; nf < 2; ++nf)
                        acc[mf][nf] = __builtin_amdgcn_mfma_f32_16x16x32_bf16(
                            a[mf], b[nf], acc[mf][nf], 0, 0, 0);
            }
            WAITLGKM();
            BAR();
        }
    }

    // ---- clip + masked store (output 1000 wide) ----
#pragma unroll
    for (int mf = 0; mf < 4; ++mf)
#pragma unroll
        for (int nf = 0; nf < 2; ++nf)
#pragma unroll
            for (int r = 0; r < 4; ++r) {
                int row = bm * 128 + wm * 64 + mf * 16 + (lane >> 4) * 4 + r;
                int col = bn * 128 + wn * 32 + nf * 16 + (lane & 15);
                if (col < NCLS) {
                    float v = acc[mf][nf][r];
                    v = fminf(fmaxf(v, 0.f), 1.f);
                    out[(size_t)row * NCLS + col] = v;
                }
            }
}

extern "C" void kernel_launch(void* const* d_in, const int* in_sizes, int n_in,
                              void* d_out, int out_size, void* d_ws, size_t ws_size,
                              hipStream_t stream) {
    const float* x = (const float*)d_in[0];
    const float* w = (const float*)d_in[1];
    const float* p = (const float*)d_in[2];
    float* out = (float*)d_out;
    char* ws = (char*)d_ws;

    __hip_bfloat16* xb    = (__hip_bfloat16*)(ws + OFF_XB);
    __hip_bfloat16* wT    = (__hip_bfloat16*)(ws + OFF_WT);
    __hip_bfloat16* pT    = (__hip_bfloat16*)(ws + OFF_PT);
    __hip_bfloat16* route = (__hip_bfloat16*)(ws + OFF_RT);

    k_cvt_all<<<9216, 256, 0, stream>>>(x, w, p, xb, wT, pT);
    k_gemm1_route<<<640, 256, 0, stream>>>(xb, wT, route);
    k_gemm2<<<256, 512, 0, stream>>>(route, pT, out);
}

// Round 13
// 85.958 us; speedup vs baseline: 1.1756x; 1.1756x over previous
//
#include <hip/hip_runtime.h>
#include <hip/hip_bf16.h>

// ---- problem constants ----
#define BATCH   4096
#define FEAT    1024
#define NTREES  10
#define NNODES  255
#define NLEAF   256
#define NCLS    1000
#define KTOT    2560          // NTREES*NLEAF

typedef __attribute__((ext_vector_type(8))) short  bf16x8;
typedef __attribute__((ext_vector_type(4))) float  f32x4;

// workspace layout (bytes)
#define OFF_XB 0u             // xb bf16 [4096][1024]      8,388,608
#define OFF_WT 8388608u       // wT bf16 [10][256][1024]   5,242,880
#define OFF_PT 13631488u      // pT bf16 [1024][2560]      5,242,880
#define OFF_RT 18874368u      // route bf16 [4096][2560]  20,971,520

#define WAITVM(N) asm volatile("s_waitcnt vmcnt(" #N ")" ::: "memory")
#define WAITLGKM() asm volatile("s_waitcnt lgkmcnt(0)" ::: "memory")
#define BAR() __builtin_amdgcn_s_barrier()

__device__ __forceinline__ void load_lds16(const void* g, void* l) {
    __builtin_amdgcn_global_load_lds(
        (const __attribute__((address_space(1))) unsigned int*)g,
        (__attribute__((address_space(3))) unsigned int*)l, 16, 0, 0);
}

// ---------------- fused conversion kernel ----------------
// blocks 0..1023: x -> bf16 (4 chunks each); 1024..3583: w transpose; 3584..6143: p transpose
__global__ void k_cvt_all(const float* __restrict__ x, const float* __restrict__ w,
                          const float* __restrict__ p,
                          __hip_bfloat16* __restrict__ xb,
                          __hip_bfloat16* __restrict__ wT,
                          __hip_bfloat16* __restrict__ pT) {
    __shared__ float tile[32][33];
    const int bid = blockIdx.x;
    const int tid = threadIdx.x;

    if (bid < 1024) {
#pragma unroll
        for (int r = 0; r < 4; ++r) {
            int i = (bid * 4 + r) * 256 + tid;
            float4 v = reinterpret_cast<const float4*>(x)[i];
            union { ushort4 u; __hip_bfloat16 h[4]; } o;
            o.h[0] = __float2bfloat16(v.x);
            o.h[1] = __float2bfloat16(v.y);
            o.h[2] = __float2bfloat16(v.z);
            o.h[3] = __float2bfloat16(v.w);
            reinterpret_cast<ushort4*>(xb)[i] = o.u;
        }
    } else if (bid < 3584) {
        int idx = bid - 1024;              // 2560: t(10) x fb(32) x nb(8)
        int t  = idx >> 8;
        int fb = ((idx >> 3) & 31) * 32;
        int nb = (idx & 7) * 32;
        int tx = tid & 31, ty = tid >> 5;
#pragma unroll
        for (int j = 0; j < 4; ++j) {
            int f = fb + ty + j * 8;
            int n = nb + tx;
            float v = (n < NNODES) ? w[((size_t)t * FEAT + f) * NNODES + n] : 0.f;
            tile[ty + j * 8][tx] = v;
        }
        __syncthreads();
#pragma unroll
        for (int j = 0; j < 4; ++j) {
            int n = nb + ty + j * 8;
            int f = fb + tx;
            wT[((size_t)t * NLEAF + n) * FEAT + f] = __float2bfloat16(tile[tx][ty + j * 8]);
        }
    } else {
        int idx = bid - 3584;              // 2560: kb(80) x cb(32)
        int cb = (idx & 31) * 32;
        int kb = (idx >> 5) * 32;
        int tx = tid & 31, ty = tid >> 5;
#pragma unroll
        for (int j = 0; j < 4; ++j) {
            int k = kb + ty + j * 8;
            int c = cb + tx;
            float v = (c < NCLS) ? p[(size_t)k * NCLS + c] * 0.1f : 0.f;
            tile[ty + j * 8][tx] = v;
        }
        __syncthreads();
#pragma unroll
        for (int j = 0; j < 4; ++j) {
            int c = cb + ty + j * 8;
            int k = kb + tx;
            pT[(size_t)c * KTOT + k] = __float2bfloat16(tile[tx][ty + j * 8]);
        }
    }
}

// ---------------- GEMM1 + sigmoid + routing (R10, verified best: 46us) ----------------
// tile 64(M) x 256(N=one tree), BK=64, 512 thr = 8 waves (2M x 4N, wave 32x64).
// dbuf 2 x 40KB = 80KB. Loop: {stage(t+1); WAITVM(5); BAR; reads+MFMA; LGKM; BAR}
__global__ __launch_bounds__(512) void k_gemm1_route(
        const __hip_bfloat16* __restrict__ xb,
        const __hip_bfloat16* __restrict__ wT,
        __hip_bfloat16* __restrict__ route) {
    __shared__ __align__(16) char smem[81920];    // 2 x (A 8KB + B 32KB); Ds[64][132] f32 reuse

    const int wg = blockIdx.x;                    // 640 blocks
    const int sw = (wg & 7) * 80 + (wg >> 3);     // 8 XCD x 80 (tree-grouped per XCD)
    const int bm = sw & 63;
    const int tr = sw >> 6;

    const int tid = threadIdx.x;
    const int lane = tid & 63, wid = tid >> 6;
    const int wm = wid >> 2, wn = wid & 3;        // 2M x 4N, wave 32x64

    f32x4 acc[2][4] = {};

    // ---- hoisted staging addresses (pre-swizzled source, linear dest) ----
    const char* gA; int lA;
    {
        int d = tid, R = d >> 3, c = d & 7, gc = c ^ (R & 7);
        gA = (const char*)xb + ((size_t)(bm * 64 + R)) * 2048 + gc * 16;
        lA = d * 16;
    }
    const char* gB[4]; int lB[4];
#pragma unroll
    for (int q = 0; q < 4; ++q) {
        int d = q * 512 + tid, R = d >> 3, c = d & 7, gc = c ^ (R & 7);
        gB[q] = (const char*)wT + ((size_t)(tr * 256 + R)) * 2048 + gc * 16;
        lB[q] = 8192 + d * 16;
    }
    // ---- hoisted fragment-read offsets ----
    int offA[2][2];                               // [mf][ks]
#pragma unroll
    for (int mf = 0; mf < 2; ++mf)
#pragma unroll
        for (int ks = 0; ks < 2; ++ks) {
            int ra = wm * 32 + mf * 16 + (lane & 15);
            int s  = ks * 4 + (lane >> 4);
            offA[mf][ks] = ra * 128 + ((s ^ (ra & 7)) << 4);
        }
    int offB[2][4];                               // [ks][nf]
#pragma unroll
    for (int ks = 0; ks < 2; ++ks)
#pragma unroll
        for (int nf = 0; nf < 4; ++nf) {
            int rb = wn * 64 + nf * 16 + (lane & 15);
            int s  = ks * 4 + (lane >> 4);
            offB[ks][nf] = 8192 + rb * 128 + ((s ^ (rb & 7)) << 4);
        }

    auto stage = [&](int t) {                     // 5 loads/thread
        char* base = smem + (t & 1) * 40960;
        load_lds16(gA + t * 128, base + lA);
#pragma unroll
        for (int q = 0; q < 4; ++q)
            load_lds16(gB[q] + t * 128, base + lB[q]);
    };

    stage(0);                                     // 5 loads in flight

#pragma unroll
    for (int t = 0; t < 16; ++t) {
        if (t < 15) { stage(t + 1); WAITVM(5); }  // tile t landed, t+1 flying
        else        { WAITVM(0); }
        BAR();

        const char* As = smem + (t & 1) * 40960;
#pragma unroll
        for (int ks = 0; ks < 2; ++ks) {
            bf16x8 a[2], b[4];
#pragma unroll
            for (int mf = 0; mf < 2; ++mf)
                a[mf] = *(const bf16x8*)(As + offA[mf][ks]);
#pragma unroll
            for (int nf = 0; nf < 4; ++nf)
                b[nf] = *(const bf16x8*)(As + offB[ks][nf]);
#pragma unroll
            for (int mf = 0; mf < 2; ++mf)
#pragma unroll
                for (int nf = 0; nf < 4; ++nf)
                    acc[mf][nf] = __builtin_amdgcn_mfma_f32_16x16x32_bf16(
                        a[mf], b[nf], acc[mf][nf], 0, 0, 0);
        }
        WAITLGKM();                               // my reads of buffer t&1 retired
        BAR();                                    // all waves done -> safe to re-stage
    }

    __syncthreads();                              // buffers dead; reuse as Ds

    // ---- epilogue (R8, verified): sigmoid nodes 0..126 -> Ds; level-7 from regs ----
    float* Ds = (float*)smem;                     // [64][132] fp32 = 33.8KB
    if (wn < 2) {
#pragma unroll
        for (int mf = 0; mf < 2; ++mf)
#pragma unroll
            for (int nf = 0; nf < 4; ++nf) {
                int col = wn * 64 + nf * 16 + (lane & 15);
                if (col < 127) {
#pragma unroll
                    for (int r = 0; r < 4; ++r) {
                        int row = wm * 32 + mf * 16 + (lane >> 4) * 4 + r;
                        float z = acc[mf][nf][r];
                        Ds[row * 132 + col] = 1.f / (1.f + __expf(-z));
                    }
                }
            }
    }
    __syncthreads();
    if (wn >= 1) {
#pragma unroll
        for (int mf = 0; mf < 2; ++mf)
#pragma unroll
            for (int nf = 0; nf < 4; ++nf) {
                int col = wn * 64 + nf * 16 + (lane & 15);
                if (col >= 127 && col <= 254) {
                    int pnode = col - 127;
#pragma unroll
                    for (int r = 0; r < 4; ++r) {
                        int row = wm * 32 + mf * 16 + (lane >> 4) * 4 + r;
                        float prefix = 1.f;
#pragma unroll
                        for (int l = 0; l < 7; ++l) {
                            int node = (1 << l) - 1 + (pnode >> (7 - l));
                            float v = Ds[row * 132 + node];
                            prefix *= (((pnode >> (6 - l)) & 1) == 0) ? v : (1.f - v);
                        }
                        float wv = 1.f / (1.f + __expf(-acc[mf][nf][r]));
                        union { unsigned int u; __hip_bfloat16 h[2]; } pk;
                        pk.h[0] = __float2bfloat16(prefix * wv);
                        pk.h[1] = __float2bfloat16(prefix * (1.f - wv));
                        int bb = bm * 64 + row;
                        *(unsigned int*)(route + (size_t)bb * KTOT + tr * NLEAF + 2 * pnode) = pk.u;
                    }
                }
            }
    }
}

// ---------------- GEMM2 + clip ----------------
// tile 128x128 (grid 256 = 1 round), BK=64, 512 thr = 8 waves (2M x 4N, wave 64x32).
// ring-3 x 32KB = 96KB, depth-2 counted vmcnt: {WAITVM(4); BAR; stage(t+2);
// reads+MFMA; LGKM; BAR}. Addresses hoisted.
__global__ __launch_bounds__(512) void k_gemm2(
        const __hip_bfloat16* __restrict__ route,
        const __hip_bfloat16* __restrict__ pT,
        float* __restrict__ out) {
    __shared__ __align__(16) char smem[98304];

    const int wg = blockIdx.x;                    // 256 blocks
    const int sw = (wg & 7) * 32 + (wg >> 3);     // 8 XCD x 32
    const int bm = sw >> 3;
    const int bn = sw & 7;

    const int tid = threadIdx.x;
    const int lane = tid & 63, wid = tid >> 6;
    const int wm = wid >> 2, wn = wid & 3;        // 2M x 4N, wave 64x32

    f32x4 acc[4][2] = {};

    const char* gA[2]; int lA[2];
    const char* gB[2]; int lB[2];
#pragma unroll
    for (int q = 0; q < 2; ++q) {
        int d = q * 512 + tid, R = d >> 3, c = d & 7, gc = c ^ (R & 7);
        gA[q] = (const char*)route + ((size_t)(bm * 128 + R)) * 5120 + gc * 16;
        lA[q] = d * 16;
        gB[q] = (const char*)pT + ((size_t)(bn * 128 + R)) * 5120 + gc * 16;
        lB[q] = 16384 + d * 16;
    }
    int offA[4][2];                               // [mf][ks]
#pragma unroll
    for (int mf = 0; mf < 4; ++mf)
#pragma unroll
        for (int ks = 0; ks < 2; ++ks) {
            int ra = wm * 64 + mf * 16 + (lane & 15);
            int s  = ks * 4 + (lane >> 4);
            offA[mf][ks] = ra * 128 + ((s ^ (ra & 7)) << 4);
        }
    int offB[2][2];                               // [ks][nf]
#pragma unroll
    for (int ks = 0; ks < 2; ++ks)
#pragma unroll
        for (int nf = 0; nf < 2; ++nf) {
            int rb = wn * 32 + nf * 16 + (lane & 15);
            int s  = ks * 4 + (lane >> 4);
            offB[ks][nf] = 16384 + rb * 128 + ((s ^ (rb & 7)) << 4);
        }

    auto stage = [&](int t) {                     // 4 loads/thread
        char* base = smem + (t % 3) * 32768;
#pragma unroll
        for (int q = 0; q < 2; ++q) {
            load_lds16(gA[q] + (size_t)t * 128, base + lA[q]);
            load_lds16(gB[q] + (size_t)t * 128, base + lB[q]);
        }
    };

    stage(0); stage(1);                           // 8 loads in flight

    for (int to = 0; to < 5; ++to) {
#pragma unroll
        for (int ti = 0; ti < 8; ++ti) {
            const int t = to * 8 + ti;
            if (t < 39) { WAITVM(4); }            // tile t landed, t+1 flying
            else        { WAITVM(0); }
            BAR();
            if (t + 2 < 40) stage(t + 2);         // slot (t+2)%3 = (t-1)%3: readers done

            const char* As = smem + (t % 3) * 32768;
#pragma unroll
            for (int ks = 0; ks < 2; ++ks) {
                bf16x8 a[4], b[2];
#pragma unroll
                for (int mf = 0; mf < 4; ++mf)
                    a[mf] = *(const bf16x8*)(As + offA[mf][ks]);
#pragma unroll
                for (int nf = 0; nf < 2; ++nf)
                    b[nf] = *(const bf16x8*)(As + offB[ks][nf]);
#pragma unroll
                for (int mf = 0; mf < 4; ++mf)
#pragma unroll
                    for (int nf = 0; nf < 2; ++nf)
                        acc[mf][nf] = __builtin_amdgcn_mfma_f32_16x16x32_bf16(
                            a[mf], b[nf], acc[mf][nf], 0, 0, 0);
            }
            WAITLGKM();                           // my reads of slot t%3 retired
            BAR();                                // safe for stage(t+3) next iter
        }
    }

    // ---- clip + masked store (output 1000 wide) ----
#pragma unroll
    for (int mf = 0; mf < 4; ++mf)
#pragma unroll
        for (int nf = 0; nf < 2; ++nf)
#pragma unroll
            for (int r = 0; r < 4; ++r) {
                int row = bm * 128 + wm * 64 + mf * 16 + (lane >> 4) * 4 + r;
                int col = bn * 128 + wn * 32 + nf * 16 + (lane & 15);
                if (col < NCLS) {
                    float v = acc[mf][nf][r];
                    v = fminf(fmaxf(v, 0.f), 1.f);
                    out[(size_t)row * NCLS + col] = v;
                }
            }
}

extern "C" void kernel_launch(void* const* d_in, const int* in_sizes, int n_in,
                              void* d_out, int out_size, void* d_ws, size_t ws_size,
                              hipStream_t stream) {
    const float* x = (const float*)d_in[0];
    const float* w = (const float*)d_in[1];
    const float* p = (const float*)d_in[2];
    float* out = (float*)d_out;
    char* ws = (char*)d_ws;

    __hip_bfloat16* xb    = (__hip_bfloat16*)(ws + OFF_XB);
    __hip_bfloat16* wT    = (__hip_bfloat16*)(ws + OFF_WT);
    __hip_bfloat16* pT    = (__hip_bfloat16*)(ws + OFF_PT);
    __hip_bfloat16* route = (__hip_bfloat16*)(ws + OFF_RT);

    k_cvt_all<<<6144, 256, 0, stream>>>(x, w, p, xb, wT, pT);
    k_gemm1_route<<<640, 512, 0, stream>>>(xb, wT, route);
    k_gemm2<<<256, 512, 0, stream>>>(route, pT, out);
}

// Round 14
// 83.991 us; speedup vs baseline: 1.2031x; 1.0234x over previous
//
#include <hip/hip_runtime.h>
#include <hip/hip_bf16.h>

// ---- problem constants ----
#define BATCH   4096
#define FEAT    1024
#define NTREES  10
#define NNODES  255
#define NLEAF   256
#define NCLS    1000
#define KTOT    2560          // NTREES*NLEAF

typedef __attribute__((ext_vector_type(8))) short  bf16x8;
typedef __attribute__((ext_vector_type(4))) float  f32x4;

// fp8 scales: route stored as fp8(route*64); P stored as fp8(P*0.1*4096)
// dequant: out = acc / (64*4096) = acc * 3.814697e-6f
#define DEQ (1.0f / 262144.0f)

// workspace layout (bytes)
#define OFF_XB 0u             // xb bf16 [4096][1024]      8,388,608
#define OFF_WT 8388608u       // wT bf16 [10][256][1024]   5,242,880
#define OFF_PT 13631488u      // pT8 fp8 [1024][2560]      2,621,440
#define OFF_RT 16252928u      // route8 fp8 [4096][2560]  10,485,760

#define WAITVM(N) asm volatile("s_waitcnt vmcnt(" #N ")" ::: "memory")
#define WAITLGKM() asm volatile("s_waitcnt lgkmcnt(0)" ::: "memory")
#define BAR() __builtin_amdgcn_s_barrier()

__device__ __forceinline__ void load_lds16(const void* g, void* l) {
    __builtin_amdgcn_global_load_lds(
        (const __attribute__((address_space(1))) unsigned int*)g,
        (__attribute__((address_space(3))) unsigned int*)l, 16, 0, 0);
}

// pack two floats -> two OCP e4m3 bytes (low 16 bits of result)
__device__ __forceinline__ unsigned short pk_fp8(float a, float b) {
    int r = __builtin_amdgcn_cvt_pk_fp8_f32(a, b, 0, false);
    return (unsigned short)(r & 0xffff);
}

// ---------------- fused conversion kernel ----------------
// blocks 0..1023: x -> bf16 (4 chunks); 1024..3583: w transpose; 3584..6143: p -> fp8 transpose
__global__ void k_cvt_all(const float* __restrict__ x, const float* __restrict__ w,
                          const float* __restrict__ p,
                          __hip_bfloat16* __restrict__ xb,
                          __hip_bfloat16* __restrict__ wT,
                          unsigned char* __restrict__ pT8) {
    __shared__ float tile[32][33];
    const int bid = blockIdx.x;
    const int tid = threadIdx.x;

    if (bid < 1024) {
#pragma unroll
        for (int r = 0; r < 4; ++r) {
            int i = (bid * 4 + r) * 256 + tid;
            float4 v = reinterpret_cast<const float4*>(x)[i];
            union { ushort4 u; __hip_bfloat16 h[4]; } o;
            o.h[0] = __float2bfloat16(v.x);
            o.h[1] = __float2bfloat16(v.y);
            o.h[2] = __float2bfloat16(v.z);
            o.h[3] = __float2bfloat16(v.w);
            reinterpret_cast<ushort4*>(xb)[i] = o.u;
        }
    } else if (bid < 3584) {
        int idx = bid - 1024;              // 2560: t(10) x fb(32) x nb(8)
        int t  = idx >> 8;
        int fb = ((idx >> 3) & 31) * 32;
        int nb = (idx & 7) * 32;
        int tx = tid & 31, ty = tid >> 5;
#pragma unroll
        for (int j = 0; j < 4; ++j) {
            int f = fb + ty + j * 8;
            int n = nb + tx;
            float v = (n < NNODES) ? w[((size_t)t * FEAT + f) * NNODES + n] : 0.f;
            tile[ty + j * 8][tx] = v;
        }
        __syncthreads();
#pragma unroll
        for (int j = 0; j < 4; ++j) {
            int n = nb + ty + j * 8;
            int f = fb + tx;
            wT[((size_t)t * NLEAF + n) * FEAT + f] = __float2bfloat16(tile[tx][ty + j * 8]);
        }
    } else {
        int idx = bid - 3584;              // 2560: kb(80) x cb(32)
        int cb = (idx & 31) * 32;
        int kb = (idx >> 5) * 32;
        int tx = tid & 31, ty = tid >> 5;
#pragma unroll
        for (int j = 0; j < 4; ++j) {
            int k = kb + ty + j * 8;
            int c = cb + tx;
            float v = (c < NCLS) ? p[(size_t)k * NCLS + c] * 409.6f : 0.f;  // 0.1*4096
            tile[ty + j * 8][tx] = v;
        }
        __syncthreads();
        if (tx < 16) {
#pragma unroll
            for (int j = 0; j < 4; ++j) {
                int c = cb + ty + j * 8;
                float f0 = tile[tx * 2][ty + j * 8];
                float f1 = tile[tx * 2 + 1][ty + j * 8];
                *(unsigned short*)(pT8 + (size_t)c * KTOT + kb + tx * 2) = pk_fp8(f0, f1);
            }
        }
    }
}

// ---------------- GEMM1 + sigmoid + routing (R10 structure, fp8 route out) ----------------
// tile 64(M) x 256(N=one tree), BK=64, 512 thr = 8 waves (2M x 4N, wave 32x64).
// dbuf 2 x 40KB = 80KB. Loop: {stage(t+1); WAITVM(5); BAR; reads+MFMA; LGKM; BAR}
__global__ __launch_bounds__(512) void k_gemm1_route(
        const __hip_bfloat16* __restrict__ xb,
        const __hip_bfloat16* __restrict__ wT,
        unsigned char* __restrict__ route8) {
    __shared__ __align__(16) char smem[81920];    // 2 x (A 8KB + B 32KB); Ds[64][132] f32 reuse

    const int wg = blockIdx.x;                    // 640 blocks
    const int sw = (wg & 7) * 80 + (wg >> 3);     // 8 XCD x 80 (tree-grouped per XCD)
    const int bm = sw & 63;
    const int tr = sw >> 6;

    const int tid = threadIdx.x;
    const int lane = tid & 63, wid = tid >> 6;
    const int wm = wid >> 2, wn = wid & 3;        // 2M x 4N, wave 32x64

    f32x4 acc[2][4] = {};

    // ---- hoisted staging addresses (pre-swizzled source, linear dest) ----
    const char* gA; int lA;
    {
        int d = tid, R = d >> 3, c = d & 7, gc = c ^ (R & 7);
        gA = (const char*)xb + ((size_t)(bm * 64 + R)) * 2048 + gc * 16;
        lA = d * 16;
    }
    const char* gB[4]; int lB[4];
#pragma unroll
    for (int q = 0; q < 4; ++q) {
        int d = q * 512 + tid, R = d >> 3, c = d & 7, gc = c ^ (R & 7);
        gB[q] = (const char*)wT + ((size_t)(tr * 256 + R)) * 2048 + gc * 16;
        lB[q] = 8192 + d * 16;
    }
    // ---- hoisted fragment-read offsets ----
    int offA[2][2];                               // [mf][ks]
#pragma unroll
    for (int mf = 0; mf < 2; ++mf)
#pragma unroll
        for (int ks = 0; ks < 2; ++ks) {
            int ra = wm * 32 + mf * 16 + (lane & 15);
            int s  = ks * 4 + (lane >> 4);
            offA[mf][ks] = ra * 128 + ((s ^ (ra & 7)) << 4);
        }
    int offB[2][4];                               // [ks][nf]
#pragma unroll
    for (int ks = 0; ks < 2; ++ks)
#pragma unroll
        for (int nf = 0; nf < 4; ++nf) {
            int rb = wn * 64 + nf * 16 + (lane & 15);
            int s  = ks * 4 + (lane >> 4);
            offB[ks][nf] = 8192 + rb * 128 + ((s ^ (rb & 7)) << 4);
        }

    auto stage = [&](int t) {                     // 5 loads/thread
        char* base = smem + (t & 1) * 40960;
        load_lds16(gA + t * 128, base + lA);
#pragma unroll
        for (int q = 0; q < 4; ++q)
            load_lds16(gB[q] + t * 128, base + lB[q]);
    };

    stage(0);                                     // 5 loads in flight

#pragma unroll
    for (int t = 0; t < 16; ++t) {
        if (t < 15) { stage(t + 1); WAITVM(5); }  // tile t landed, t+1 flying
        else        { WAITVM(0); }
        BAR();

        const char* As = smem + (t & 1) * 40960;
#pragma unroll
        for (int ks = 0; ks < 2; ++ks) {
            bf16x8 a[2], b[4];
#pragma unroll
            for (int mf = 0; mf < 2; ++mf)
                a[mf] = *(const bf16x8*)(As + offA[mf][ks]);
#pragma unroll
            for (int nf = 0; nf < 4; ++nf)
                b[nf] = *(const bf16x8*)(As + offB[ks][nf]);
#pragma unroll
            for (int mf = 0; mf < 2; ++mf)
#pragma unroll
                for (int nf = 0; nf < 4; ++nf)
                    acc[mf][nf] = __builtin_amdgcn_mfma_f32_16x16x32_bf16(
                        a[mf], b[nf], acc[mf][nf], 0, 0, 0);
        }
        WAITLGKM();                               // my reads of buffer t&1 retired
        BAR();                                    // all waves done -> safe to re-stage
    }

    __syncthreads();                              // buffers dead; reuse as Ds

    // ---- epilogue: sigmoid nodes 0..126 -> Ds; level-7 from regs; 2 fp8 leaves packed
    float* Ds = (float*)smem;                     // [64][132] fp32 = 33.8KB
    if (wn < 2) {
#pragma unroll
        for (int mf = 0; mf < 2; ++mf)
#pragma unroll
            for (int nf = 0; nf < 4; ++nf) {
                int col = wn * 64 + nf * 16 + (lane & 15);
                if (col < 127) {
#pragma unroll
                    for (int r = 0; r < 4; ++r) {
                        int row = wm * 32 + mf * 16 + (lane >> 4) * 4 + r;
                        float z = acc[mf][nf][r];
                        Ds[row * 132 + col] = 1.f / (1.f + __expf(-z));
                    }
                }
            }
    }
    __syncthreads();
    if (wn >= 1) {
#pragma unroll
        for (int mf = 0; mf < 2; ++mf)
#pragma unroll
            for (int nf = 0; nf < 4; ++nf) {
                int col = wn * 64 + nf * 16 + (lane & 15);
                if (col >= 127 && col <= 254) {
                    int pnode = col - 127;
#pragma unroll
                    for (int r = 0; r < 4; ++r) {
                        int row = wm * 32 + mf * 16 + (lane >> 4) * 4 + r;
                        float prefix = 1.f;
#pragma unroll
                        for (int l = 0; l < 7; ++l) {
                            int node = (1 << l) - 1 + (pnode >> (7 - l));
                            float v = Ds[row * 132 + node];
                            prefix *= (((pnode >> (6 - l)) & 1) == 0) ? v : (1.f - v);
                        }
                        float wv = 1.f / (1.f + __expf(-acc[mf][nf][r]));
                        // route stored as fp8(route * 64)
                        unsigned short pk = pk_fp8(prefix * wv * 64.f,
                                                   prefix * (1.f - wv) * 64.f);
                        int bb = bm * 64 + row;
                        *(unsigned short*)(route8 + (size_t)bb * KTOT + tr * NLEAF + 2 * pnode) = pk;
                    }
                }
            }
    }
}

// ---------------- GEMM2 (fp8) + clip ----------------
// tile 128x128 (grid 256 = 1 round), BK=128 (128B fp8 rows -> same XOR-8 swizzle),
// 512 thr = 8 waves (2M x 4N, wave 64x32). ring-3 x 32KB = 96KB, depth-2 counted
// vmcnt. NT=20. Fragment reads: ds_read_b64 (8 fp8 = one MFMA operand), <=2-way banks.
__global__ __launch_bounds__(512) void k_gemm2(
        const unsigned char* __restrict__ route8,
        const unsigned char* __restrict__ pT8,
        float* __restrict__ out) {
    __shared__ __align__(16) char smem[98304];

    const int wg = blockIdx.x;                    // 256 blocks
    const int sw = (wg & 7) * 32 + (wg >> 3);     // 8 XCD x 32
    const int bm = sw >> 3;
    const int bn = sw & 7;

    const int tid = threadIdx.x;
    const int lane = tid & 63, wid = tid >> 6;
    const int wm = wid >> 2, wn = wid & 3;        // 2M x 4N, wave 64x32

    f32x4 acc[4][2] = {};

    // staging: A 128 rows x 128B = 16KB (1024 chunks), B same; 2+2 loads/thread
    const char* gA[2]; int lA[2];
    const char* gB[2]; int lB[2];
#pragma unroll
    for (int q = 0; q < 2; ++q) {
        int d = q * 512 + tid, R = d >> 3, c = d & 7, gc = c ^ (R & 7);
        gA[q] = (const char*)route8 + (size_t)(bm * 128 + R) * KTOT + gc * 16;
        lA[q] = d * 16;
        gB[q] = (const char*)pT8 + (size_t)(bn * 128 + R) * KTOT + gc * 16;
        lB[q] = 16384 + d * 16;
    }
    // fragment-read offsets: row r, K-step ks (0..3), lane group g = lane>>4
    // byte = r*128 + (((ks*2 + (g>>1)) ^ (r&7))<<4) + (g&1)*8
    const int g = lane >> 4;
    int offA[4][4];                               // [mf][ks]
#pragma unroll
    for (int mf = 0; mf < 4; ++mf)
#pragma unroll
        for (int ks = 0; ks < 4; ++ks) {
            int ra = wm * 64 + mf * 16 + (lane & 15);
            offA[mf][ks] = ra * 128 + (((ks * 2 + (g >> 1)) ^ (ra & 7)) << 4) + (g & 1) * 8;
        }
    int offB[2][4];                               // [nf][ks]
#pragma unroll
    for (int nf = 0; nf < 2; ++nf)
#pragma unroll
        for (int ks = 0; ks < 4; ++ks) {
            int rb = wn * 32 + nf * 16 + (lane & 15);
            offB[nf][ks] = 16384 + rb * 128 + (((ks * 2 + (g >> 1)) ^ (rb & 7)) << 4) + (g & 1) * 8;
        }

    auto stage = [&](int t) {                     // 4 loads/thread; t in BK=128 units
        char* base = smem + (t % 3) * 32768;
#pragma unroll
        for (int q = 0; q < 2; ++q) {
            load_lds16(gA[q] + (size_t)t * 128, base + lA[q]);
            load_lds16(gB[q] + (size_t)t * 128, base + lB[q]);
        }
    };

    stage(0); stage(1);                           // 8 loads in flight

    const int NT = KTOT / 128;                    // 20
#pragma unroll 4
    for (int t = 0; t < NT; ++t) {
        if (t < NT - 1) { WAITVM(4); }            // tile t landed, t+1 flying
        else            { WAITVM(0); }
        BAR();
        if (t + 2 < NT) stage(t + 2);             // slot (t+2)%3 = (t-1)%3: readers done

        const char* As = smem + (t % 3) * 32768;
#pragma unroll
        for (int ks = 0; ks < 4; ++ks) {
            long a[4], b[2];
#pragma unroll
            for (int mf = 0; mf < 4; ++mf)
                a[mf] = *(const long*)(As + offA[mf][ks]);
#pragma unroll
            for (int nf = 0; nf < 2; ++nf)
                b[nf] = *(const long*)(As + offB[nf][ks]);
#pragma unroll
            for (int mf = 0; mf < 4; ++mf)
#pragma unroll
                for (int nf = 0; nf < 2; ++nf)
                    acc[mf][nf] = __builtin_amdgcn_mfma_f32_16x16x32_fp8_fp8(
                        a[mf], b[nf], acc[mf][nf], 0, 0, 0);
        }
        WAITLGKM();                               // my reads of slot t%3 retired
        BAR();                                    // safe for stage(t+3) next iter
    }

    // ---- dequant + clip + masked store (output 1000 wide) ----
#pragma unroll
    for (int mf = 0; mf < 4; ++mf)
#pragma unroll
        for (int nf = 0; nf < 2; ++nf)
#pragma unroll
            for (int r = 0; r < 4; ++r) {
                int row = bm * 128 + wm * 64 + mf * 16 + (lane >> 4) * 4 + r;
                int col = bn * 128 + wn * 32 + nf * 16 + (lane & 15);
                if (col < NCLS) {
                    float v = acc[mf][nf][r] * DEQ;
                    v = fminf(fmaxf(v, 0.f), 1.f);
                    out[(size_t)row * NCLS + col] = v;
                }
            }
}

extern "C" void kernel_launch(void* const* d_in, const int* in_sizes, int n_in,
                              void* d_out, int out_size, void* d_ws, size_t ws_size,
                              hipStream_t stream) {
    const float* x = (const float*)d_in[0];
    const float* w = (const float*)d_in[1];
    const float* p = (const float*)d_in[2];
    float* out = (float*)d_out;
    char* ws = (char*)d_ws;

    __hip_bfloat16* xb     = (__hip_bfloat16*)(ws + OFF_XB);
    __hip_bfloat16* wT     = (__hip_bfloat16*)(ws + OFF_WT);
    unsigned char*  pT8    = (unsigned char*)(ws + OFF_PT);
    unsigned char*  route8 = (unsigned char*)(ws + OFF_RT);

    k_cvt_all<<<6144, 256, 0, stream>>>(x, w, p, xb, wT, pT8);
    k_gemm1_route<<<640, 512, 0, stream>>>(xb, wT, route8);
    k_gemm2<<<256, 512, 0, stream>>>(route8, pT8, out);
}